// Round 2
// baseline (1243.883 us; speedup 1.0000x reference)
//
#include <hip/hip_runtime.h>

#define BT 256
#define HID 2048
#define NE 8
#define INTER 4096

typedef short short8 __attribute__((ext_vector_type(8)));
typedef float f32x4 __attribute__((ext_vector_type(4)));

__device__ inline unsigned short f2bf(float f){
  unsigned int u = __float_as_uint(f);
  u += 0x7fff + ((u >> 16) & 1);   // round-to-nearest-even
  return (unsigned short)(u >> 16);
}
__device__ inline ushort4 f2bf4(float4 v){
  ushort4 b; b.x=f2bf(v.x); b.y=f2bf(v.y); b.z=f2bf(v.z); b.w=f2bf(v.w); return b;
}

// ---------------- routing: per-expert token lists (last-write-wins on dup) ----------------
__global__ void routing_kernel(const int* __restrict__ sel, const float* __restrict__ rw,
                               int* counts, int* bases, int* tokl, float* wtl){
  __shared__ int cnt[NE]; __shared__ int bs[NE]; __shared__ int cur[NE];
  int t = threadIdx.x;
  if (t < NE) cnt[t] = 0;
  __syncthreads();
  int s0 = sel[2*t], s1 = sel[2*t+1];
  float w0 = rw[2*t], w1 = rw[2*t+1];
  bool dup = (s0 == s1);
  atomicAdd(&cnt[s1], 1);
  if (!dup) atomicAdd(&cnt[s0], 1);
  __syncthreads();
  if (t == 0){ int a = 0; for (int e = 0; e < NE; e++){ bs[e] = a; cur[e] = a; a += cnt[e]; } }
  __syncthreads();
  int slot = atomicAdd(&cur[s1], 1); tokl[slot] = t; wtl[slot] = w1;
  if (!dup){ slot = atomicAdd(&cur[s0], 1); tokl[slot] = t; wtl[slot] = w0; }
  if (t < NE){ counts[t] = cnt[t]; bases[t] = bs[t]; }
}

// ---------------- gemm1: up/gate = hs @ w13^T, cur = silu(up)*gate ----------------
// grid (INTER/64, 4, NE), block 256. Tile M=64 x F=64 (both s), BK=64.
// Register-prefetch pipeline: issue tile t+1 loads, MFMA tile t from LDS, sync, store, sync.
__global__ __launch_bounds__(256) void gemm1_kernel(
    const float* __restrict__ hs, const float* __restrict__ w13,
    const int* __restrict__ counts, const int* __restrict__ bases,
    const int* __restrict__ tokl, unsigned short* __restrict__ cur)
{
  const int e = blockIdx.z;
  const int cnt = counts[e];
  const int mtile = blockIdx.y;
  if (mtile * 64 >= cnt) return;
  const int f0 = blockIdx.x * 64;
  const int base = bases[e];
  const int tid = threadIdx.x;

  __shared__ unsigned short As[64][72];
  __shared__ unsigned short Bs[2][64][72];

  const int lr = tid >> 4, c4 = tid & 15;

  const float* aptr[4];
#pragma unroll
  for (int p = 0; p < 4; p++){
    int slot = mtile*64 + p*16 + lr; if (slot >= cnt) slot = cnt - 1;
    aptr[p] = hs + (size_t)tokl[base + slot] * HID + c4*4;
  }
  const float* bptr = w13 + (size_t)e * 2*INTER*HID + (size_t)(f0 + lr) * HID + c4*4;

  const int wv = tid >> 6, wm = wv >> 1, wn = wv & 1;
  const int lane = tid & 63;
  const int lrow = lane & 15, lko = (lane >> 4)*8, quad = lane >> 4;

  f32x4 acc[2][2][2];
#pragma unroll
  for (int s=0;s<2;s++) for (int mt=0;mt<2;mt++) for (int nt=0;nt<2;nt++)
    acc[s][mt][nt] = (f32x4){0.f,0.f,0.f,0.f};

  float4 ra[4], rb[2][4];
  // prologue: tile 0 load + store
#pragma unroll
  for (int p=0;p<4;p++) ra[p] = *(const float4*)(aptr[p]);
#pragma unroll
  for (int s=0;s<2;s++)
#pragma unroll
    for (int p=0;p<4;p++)
      rb[s][p] = *(const float4*)(bptr + (size_t)(s*INTER + p*16) * HID);
#pragma unroll
  for (int p=0;p<4;p++) *(ushort4*)&As[p*16+lr][c4*4] = f2bf4(ra[p]);
#pragma unroll
  for (int s=0;s<2;s++)
#pragma unroll
    for (int p=0;p<4;p++) *(ushort4*)&Bs[s][p*16+lr][c4*4] = f2bf4(rb[s][p]);
  __syncthreads();

  for (int t = 0; t < 31; t++){
    const int k1 = (t+1)*64;
    // batch-issue next tile's loads (all in flight during MFMA below)
#pragma unroll
    for (int p=0;p<4;p++) ra[p] = *(const float4*)(aptr[p] + k1);
#pragma unroll
    for (int s=0;s<2;s++)
#pragma unroll
      for (int p=0;p<4;p++)
        rb[s][p] = *(const float4*)(bptr + (size_t)(s*INTER + p*16) * HID + k1);
    // MFMA on tile t
#pragma unroll
    for (int ks = 0; ks < 64; ks += 32){
      short8 a[2], b[2][2];
#pragma unroll
      for (int mt=0;mt<2;mt++) a[mt] = *(const short8*)&As[wm*32+mt*16+lrow][ks+lko];
#pragma unroll
      for (int s=0;s<2;s++)
#pragma unroll
        for (int nt=0;nt<2;nt++)
          b[s][nt] = *(const short8*)&Bs[s][wn*32+nt*16+lrow][ks+lko];
#pragma unroll
      for (int s=0;s<2;s++)
#pragma unroll
        for (int mt=0;mt<2;mt++)
#pragma unroll
          for (int nt=0;nt<2;nt++)
            acc[s][mt][nt] = __builtin_amdgcn_mfma_f32_16x16x32_bf16(a[mt], b[s][nt], acc[s][mt][nt], 0,0,0);
    }
    __syncthreads();
#pragma unroll
    for (int p=0;p<4;p++) *(ushort4*)&As[p*16+lr][c4*4] = f2bf4(ra[p]);
#pragma unroll
    for (int s=0;s<2;s++)
#pragma unroll
      for (int p=0;p<4;p++) *(ushort4*)&Bs[s][p*16+lr][c4*4] = f2bf4(rb[s][p]);
    __syncthreads();
  }
  // final tile
#pragma unroll
  for (int ks = 0; ks < 64; ks += 32){
    short8 a[2], b[2][2];
#pragma unroll
    for (int mt=0;mt<2;mt++) a[mt] = *(const short8*)&As[wm*32+mt*16+lrow][ks+lko];
#pragma unroll
    for (int s=0;s<2;s++)
#pragma unroll
      for (int nt=0;nt<2;nt++)
        b[s][nt] = *(const short8*)&Bs[s][wn*32+nt*16+lrow][ks+lko];
#pragma unroll
    for (int s=0;s<2;s++)
#pragma unroll
      for (int mt=0;mt<2;mt++)
#pragma unroll
        for (int nt=0;nt<2;nt++)
          acc[s][mt][nt] = __builtin_amdgcn_mfma_f32_16x16x32_bf16(a[mt], b[s][nt], acc[s][mt][nt], 0,0,0);
  }

  // epilogue: silu(up)*gate -> bf16
#pragma unroll
  for (int mt = 0; mt < 2; mt++){
#pragma unroll
    for (int reg = 0; reg < 4; reg++){
      int m = mtile*64 + wm*32 + mt*16 + quad*4 + reg;
      if (m >= cnt) continue;
      size_t rowoff = (size_t)(base + m) * INTER;
#pragma unroll
      for (int nt = 0; nt < 2; nt++){
        int i = f0 + wn*32 + nt*16 + lrow;
        float up   = acc[0][mt][nt][reg];
        float gate = acc[1][mt][nt][reg];
        float sv = up / (1.f + __expf(-up));
        cur[rowoff + i] = f2bf(sv * gate);
      }
    }
  }
}

// ---------------- gemm2: down = cur @ w2^T, out += weight * down ----------------
// grid (HID/32, 4, NE), block 256. Tile M=64 x H=32, BK=64, reg-prefetch pipeline.
__global__ __launch_bounds__(256) void gemm2_kernel(
    const unsigned short* __restrict__ cur, const float* __restrict__ w2,
    const int* __restrict__ counts, const int* __restrict__ bases,
    const int* __restrict__ tokl, const float* __restrict__ wtl,
    float* __restrict__ out)
{
  const int e = blockIdx.z;
  const int cnt = counts[e];
  const int mtile = blockIdx.y;
  if (mtile * 64 >= cnt) return;
  const int h0 = blockIdx.x * 32;
  const int base = bases[e];
  const int tid = threadIdx.x;

  __shared__ unsigned short As[64][72];
  __shared__ unsigned short Bs[32][72];

  const int r2 = tid >> 3, c8 = tid & 7;   // A: 2 rows x 16B per thread
  const unsigned short* aptr[2];
#pragma unroll
  for (int p = 0; p < 2; p++){
    int slot = mtile*64 + p*32 + r2; if (slot >= cnt) slot = cnt - 1;
    aptr[p] = cur + (size_t)(base + slot) * INTER + c8*8;
  }
  const int lr = tid >> 4, c4 = tid & 15;
  const float* bptr = w2 + (size_t)e * HID * INTER + (size_t)(h0 + lr) * INTER + c4*4;

  const int wv = tid >> 6, wm = wv >> 1, wn = wv & 1;
  const int lane = tid & 63;
  const int lrow = lane & 15, lko = (lane >> 4)*8, quad = lane >> 4;

  f32x4 acc[2];
  acc[0] = (f32x4){0.f,0.f,0.f,0.f};
  acc[1] = (f32x4){0.f,0.f,0.f,0.f};

  uint4 raa[2]; float4 rbb[2];
  // prologue
#pragma unroll
  for (int p=0;p<2;p++) raa[p] = *(const uint4*)(aptr[p]);
#pragma unroll
  for (int p=0;p<2;p++) rbb[p] = *(const float4*)(bptr + (size_t)(p*16) * INTER);
#pragma unroll
  for (int p=0;p<2;p++) *(uint4*)&As[p*32 + r2][c8*8] = raa[p];
#pragma unroll
  for (int p=0;p<2;p++) *(ushort4*)&Bs[p*16 + lr][c4*4] = f2bf4(rbb[p]);
  __syncthreads();

  for (int t = 0; t < 63; t++){
    const int k1 = (t+1)*64;
#pragma unroll
    for (int p=0;p<2;p++) raa[p] = *(const uint4*)(aptr[p] + k1);
#pragma unroll
    for (int p=0;p<2;p++) rbb[p] = *(const float4*)(bptr + (size_t)(p*16) * INTER + k1);
#pragma unroll
    for (int ks = 0; ks < 64; ks += 32){
      short8 a[2], b;
#pragma unroll
      for (int mt=0;mt<2;mt++) a[mt] = *(const short8*)&As[wm*32+mt*16+lrow][ks+lko];
      b = *(const short8*)&Bs[wn*16 + lrow][ks+lko];
#pragma unroll
      for (int mt=0;mt<2;mt++)
        acc[mt] = __builtin_amdgcn_mfma_f32_16x16x32_bf16(a[mt], b, acc[mt], 0,0,0);
    }
    __syncthreads();
#pragma unroll
    for (int p=0;p<2;p++) *(uint4*)&As[p*32 + r2][c8*8] = raa[p];
#pragma unroll
    for (int p=0;p<2;p++) *(ushort4*)&Bs[p*16 + lr][c4*4] = f2bf4(rbb[p]);
    __syncthreads();
  }
#pragma unroll
  for (int ks = 0; ks < 64; ks += 32){
    short8 a[2], b;
#pragma unroll
    for (int mt=0;mt<2;mt++) a[mt] = *(const short8*)&As[wm*32+mt*16+lrow][ks+lko];
    b = *(const short8*)&Bs[wn*16 + lrow][ks+lko];
#pragma unroll
    for (int mt=0;mt<2;mt++)
      acc[mt] = __builtin_amdgcn_mfma_f32_16x16x32_bf16(a[mt], b, acc[mt], 0,0,0);
  }

#pragma unroll
  for (int mt = 0; mt < 2; mt++){
#pragma unroll
    for (int reg = 0; reg < 4; reg++){
      int m = mtile*64 + wm*32 + mt*16 + quad*4 + reg;
      if (m >= cnt) continue;
      int tk  = tokl[base + m];
      float w = wtl[base + m];
      int h = h0 + wn*16 + lrow;
      atomicAdd(&out[(size_t)tk * HID + h], w * acc[mt][reg]);
    }
  }
}

extern "C" void kernel_launch(void* const* d_in, const int* in_sizes, int n_in,
                              void* d_out, int out_size, void* d_ws, size_t ws_size,
                              hipStream_t stream){
  const float* hs  = (const float*)d_in[0];
  const int*   sel = (const int*)d_in[1];
  const float* rw  = (const float*)d_in[2];
  const float* w13 = (const float*)d_in[3];
  const float* w2  = (const float*)d_in[4];
  float* out = (float*)d_out;
  char* ws = (char*)d_ws;

  int* counts = (int*)ws;                  // 8
  int* bases  = counts + 8;                // 8
  int* tokl   = bases + 8;                 // 512
  float* wtl  = (float*)(tokl + 512);      // 512
  unsigned short* cur = (unsigned short*)(ws + 8192);  // 512*4096 bf16 = 4 MiB

  hipMemsetAsync(d_out, 0, (size_t)BT * HID * sizeof(float), stream);
  routing_kernel<<<1, 256, 0, stream>>>(sel, rw, counts, bases, tokl, wtl);
  dim3 g1(INTER/64, 4, NE);
  gemm1_kernel<<<g1, 256, 0, stream>>>(hs, w13, counts, bases, tokl, cur);
  dim3 g2(HID/32, 4, NE);
  gemm2_kernel<<<g2, 256, 0, stream>>>(cur, w2, counts, bases, tokl, wtl, out);
}

// Round 3
// 924.704 us; speedup vs baseline: 1.3452x; 1.3452x over previous
//
#include <hip/hip_runtime.h>

#define BT 256
#define HID 2048
#define NE 8
#define INTER 4096

typedef short short8 __attribute__((ext_vector_type(8)));
typedef float f32x4 __attribute__((ext_vector_type(4)));

__device__ inline unsigned short f2bf(float f){
  unsigned int u = __float_as_uint(f);
  u += 0x7fff + ((u >> 16) & 1);   // RNE
  return (unsigned short)(u >> 16);
}
__device__ inline unsigned int pk2(float x, float y){
  return (unsigned int)f2bf(x) | ((unsigned int)f2bf(y) << 16);
}
__device__ inline short8 cvt8(float4 a, float4 b){
  union { unsigned int u[4]; short8 s; } r;
  r.u[0] = pk2(a.x, a.y); r.u[1] = pk2(a.z, a.w);
  r.u[2] = pk2(b.x, b.y); r.u[3] = pk2(b.z, b.w);
  return r.s;
}

// async 16B global->LDS DMA; side-effecting: cannot be sunk past barriers.
__device__ inline void glds16(const void* g, void* l){
  __builtin_amdgcn_global_load_lds(
      (const __attribute__((address_space(1))) unsigned int*)g,
      (__attribute__((address_space(3))) unsigned int*)l, 16, 0, 0);
}

// --- swizzled LDS tiles (rows of 64 elems; 8 chunks of 8 elems; chunk' = chunk ^ (row&7)) ---
// fp32 tile: frag = 8 consecutive fp32 at (row, kbase), kbase%8==0 -> bf16 short8
__device__ inline short8 fragf(const float* tile, int row, int kbase){
  int cp = (kbase >> 3) ^ (row & 7);
  const float4* p = (const float4*)(tile + row*64 + cp*8);
  return cvt8(p[0], p[1]);
}
// bf16 tile
__device__ inline short8 fragh(const unsigned short* tile, int row, int kbase){
  int cp = (kbase >> 3) ^ (row & 7);
  return *(const short8*)(tile + row*64 + cp*8);
}

// ---------------- routing ----------------
__global__ void routing_kernel(const int* __restrict__ sel, const float* __restrict__ rw,
                               int* counts, int* bases, int* tokl, float* wtl){
  __shared__ int cnt[NE]; __shared__ int bs[NE]; __shared__ int cur[NE];
  int t = threadIdx.x;
  if (t < NE) cnt[t] = 0;
  __syncthreads();
  int s0 = sel[2*t], s1 = sel[2*t+1];
  float w0 = rw[2*t], w1 = rw[2*t+1];
  bool dup = (s0 == s1);
  atomicAdd(&cnt[s1], 1);
  if (!dup) atomicAdd(&cnt[s0], 1);
  __syncthreads();
  if (t == 0){ int a = 0; for (int e = 0; e < NE; e++){ bs[e] = a; cur[e] = a; a += cnt[e]; } }
  __syncthreads();
  int slot = atomicAdd(&cur[s1], 1); tokl[slot] = t; wtl[slot] = w1;
  if (!dup){ slot = atomicAdd(&cur[s0], 1); tokl[slot] = t; wtl[slot] = w0; }
  if (t < NE){ counts[t] = cnt[t]; bases[t] = bs[t]; }
}

// ---------------- gemm1: up/gate = hs @ w13^T, cur = silu(up)*gate ----------------
// grid (INTER/64=64, 4, NE). Tile M=64, N=64 i-cols x {up,gate}, Ktile=64.
// LDS: As 16KB fp32 + Bs 32KB fp32 (128 w13 rows) = 48KB -> 3 blocks/CU.
__global__ __launch_bounds__(256, 3) void gemm1_kernel(
    const float* __restrict__ hs, const float* __restrict__ w13,
    const int* __restrict__ counts, const int* __restrict__ bases,
    const int* __restrict__ tokl, unsigned short* __restrict__ cur)
{
  const int e = blockIdx.z;
  const int cnt = counts[e];
  const int mtile = blockIdx.y;
  if (mtile * 64 >= cnt) return;
  const int f0 = blockIdx.x * 64;
  const int base = bases[e];
  const int tid = threadIdx.x;

  __shared__ __align__(16) float As[64*64];     // 16 KB
  __shared__ __align__(16) float Bs[128*64];    // 32 KB

  // fill descriptors: thread covers LDS bytes [off, off+16) per round
  const float* gA[4]; int offA[4];
#pragma unroll
  for (int r = 0; r < 4; r++){
    int off = r*4096 + tid*16;
    int row = off >> 8, b = off & 255;
    int cp = b >> 5, half = (b >> 4) & 1;
    int col = ((cp ^ (row & 7)) * 8) + half*4;
    int slot = mtile*64 + row; if (slot >= cnt) slot = cnt - 1;
    gA[r] = hs + (size_t)tokl[base + slot] * HID + col;
    offA[r] = off;
  }
  const float* gB[8]; int offB[8];
#pragma unroll
  for (int r = 0; r < 8; r++){
    int off = r*4096 + tid*16;
    int row = off >> 8, b = off & 255;
    int cp = b >> 5, half = (b >> 4) & 1;
    int col = ((cp ^ (row & 7)) * 8) + half*4;
    int wrow = (row < 64) ? (f0 + row) : (INTER + f0 + row - 64);
    gB[r] = w13 + (size_t)e * 2*INTER*HID + (size_t)wrow * HID + col;
    offB[r] = off;
  }

  const int wv = tid >> 6, wm = wv >> 1, wn = wv & 1;
  const int lane = tid & 63;
  const int lrow = lane & 15, quad = lane >> 4;

  f32x4 acc[2][2][2];   // [s][mt][ntp]
#pragma unroll
  for (int s=0;s<2;s++) for (int mt=0;mt<2;mt++) for (int nt=0;nt<2;nt++)
    acc[s][mt][nt] = (f32x4){0.f,0.f,0.f,0.f};

  for (int k0 = 0; k0 < HID; k0 += 64){
#pragma unroll
    for (int r = 0; r < 4; r++) glds16(gA[r] + k0, (char*)As + offA[r]);
#pragma unroll
    for (int r = 0; r < 8; r++) glds16(gB[r] + k0, (char*)Bs + offB[r]);
    __syncthreads();   // drains vmcnt (DMA complete), then barrier
#pragma unroll
    for (int ks = 0; ks < 64; ks += 32){
      int kb = ks + quad*8;
      short8 a[2], bb[2][2];
#pragma unroll
      for (int mt=0;mt<2;mt++) a[mt] = fragf(As, wm*32 + mt*16 + lrow, kb);
#pragma unroll
      for (int s=0;s<2;s++)
#pragma unroll
        for (int nt=0;nt<2;nt++)
          bb[s][nt] = fragf(Bs, s*64 + wn*32 + nt*16 + lrow, kb);
#pragma unroll
      for (int s=0;s<2;s++)
#pragma unroll
        for (int mt=0;mt<2;mt++)
#pragma unroll
          for (int nt=0;nt<2;nt++)
            acc[s][mt][nt] = __builtin_amdgcn_mfma_f32_16x16x32_bf16(
                a[mt], bb[s][nt], acc[s][mt][nt], 0,0,0);
    }
    __syncthreads();   // all reads done before next DMA overwrites
  }

  // epilogue: silu(up)*gate -> bf16 cur
#pragma unroll
  for (int mt = 0; mt < 2; mt++){
#pragma unroll
    for (int reg = 0; reg < 4; reg++){
      int m = mtile*64 + wm*32 + mt*16 + quad*4 + reg;
      if (m >= cnt) continue;
      size_t rowoff = (size_t)(base + m) * INTER;
#pragma unroll
      for (int nt = 0; nt < 2; nt++){
        int i = f0 + wn*32 + nt*16 + lrow;
        float up   = acc[0][mt][nt][reg];
        float gate = acc[1][mt][nt][reg];
        float sv = up / (1.f + __expf(-up));
        cur[rowoff + i] = f2bf(sv * gate);
      }
    }
  }
}

// ---------------- gemm2: out += w * (cur @ w2^T), split-K x2 ----------------
// grid (HID/32=64, 4, NE*2). Tile M=64, H=32, Kchunk=2048, Ktile=64.
// LDS: Ah 8KB bf16 + Bs 8KB fp32 = 16KB.
__global__ __launch_bounds__(256, 4) void gemm2_kernel(
    const unsigned short* __restrict__ cur, const float* __restrict__ w2,
    const int* __restrict__ counts, const int* __restrict__ bases,
    const int* __restrict__ tokl, const float* __restrict__ wtl,
    float* __restrict__ out)
{
  const int e  = blockIdx.z >> 1;
  const int kb0 = (blockIdx.z & 1) * 2048;
  const int cnt = counts[e];
  const int mtile = blockIdx.y;
  if (mtile * 64 >= cnt) return;
  const int h0 = blockIdx.x * 32;
  const int base = bases[e];
  const int tid = threadIdx.x;

  __shared__ __align__(16) unsigned short Ah[64*64];  // 8 KB bf16
  __shared__ __align__(16) float Bs[32*64];           // 8 KB fp32

  const unsigned short* gA[2]; int offA[2];
#pragma unroll
  for (int r = 0; r < 2; r++){
    int off = r*4096 + tid*16;
    int row = off >> 7;                 // 128 B per bf16 row
    int cp = (off >> 4) & 7;
    int col = (cp ^ (row & 7)) * 8;     // bf16 elems
    int slot = mtile*64 + row; if (slot >= cnt) slot = cnt - 1;
    gA[r] = cur + (size_t)(base + slot) * INTER + kb0 + col;
    offA[r] = off;
  }
  const float* gB[2]; int offB[2];
#pragma unroll
  for (int r = 0; r < 2; r++){
    int off = r*4096 + tid*16;
    int row = off >> 8, b = off & 255;
    int cp = b >> 5, half = (b >> 4) & 1;
    int col = ((cp ^ (row & 7)) * 8) + half*4;
    gB[r] = w2 + (size_t)e * HID * INTER + (size_t)(h0 + row) * INTER + kb0 + col;
    offB[r] = off;
  }

  const int wv = tid >> 6, wm = wv >> 1, wn = wv & 1;
  const int lane = tid & 63;
  const int lrow = lane & 15, quad = lane >> 4;

  f32x4 acc[2];
  acc[0] = (f32x4){0.f,0.f,0.f,0.f};
  acc[1] = (f32x4){0.f,0.f,0.f,0.f};

  for (int k0 = 0; k0 < 2048; k0 += 64){
#pragma unroll
    for (int r = 0; r < 2; r++) glds16(gA[r] + k0, (char*)Ah + offA[r]);
#pragma unroll
    for (int r = 0; r < 2; r++) glds16(gB[r] + k0, (char*)Bs + offB[r]);
    __syncthreads();
#pragma unroll
    for (int ks = 0; ks < 64; ks += 32){
      int kb = ks + quad*8;
      short8 a[2], b;
#pragma unroll
      for (int mt=0;mt<2;mt++) a[mt] = fragh(Ah, wm*32 + mt*16 + lrow, kb);
      b = fragf(Bs, wn*16 + lrow, kb);
#pragma unroll
      for (int mt=0;mt<2;mt++)
        acc[mt] = __builtin_amdgcn_mfma_f32_16x16x32_bf16(a[mt], b, acc[mt], 0,0,0);
    }
    __syncthreads();
  }

#pragma unroll
  for (int mt = 0; mt < 2; mt++){
#pragma unroll
    for (int reg = 0; reg < 4; reg++){
      int m = mtile*64 + wm*32 + mt*16 + quad*4 + reg;
      if (m >= cnt) continue;
      int tk  = tokl[base + m];
      float w = wtl[base + m];
      int h = h0 + wn*16 + lrow;
      atomicAdd(&out[(size_t)tk * HID + h], w * acc[mt][reg]);
    }
  }
}

extern "C" void kernel_launch(void* const* d_in, const int* in_sizes, int n_in,
                              void* d_out, int out_size, void* d_ws, size_t ws_size,
                              hipStream_t stream){
  const float* hs  = (const float*)d_in[0];
  const int*   sel = (const int*)d_in[1];
  const float* rw  = (const float*)d_in[2];
  const float* w13 = (const float*)d_in[3];
  const float* w2  = (const float*)d_in[4];
  float* out = (float*)d_out;
  char* ws = (char*)d_ws;

  int* counts = (int*)ws;                  // 8
  int* bases  = counts + 8;                // 8
  int* tokl   = bases + 8;                 // 512
  float* wtl  = (float*)(tokl + 512);      // 512
  unsigned short* cur = (unsigned short*)(ws + 8192);  // 512*4096 bf16 = 4 MiB

  hipMemsetAsync(d_out, 0, (size_t)BT * HID * sizeof(float), stream);
  routing_kernel<<<1, 256, 0, stream>>>(sel, rw, counts, bases, tokl, wtl);
  dim3 g1(INTER/64, 4, NE);
  gemm1_kernel<<<g1, 256, 0, stream>>>(hs, w13, counts, bases, tokl, cur);
  dim3 g2(HID/32, 4, NE*2);
  gemm2_kernel<<<g2, 256, 0, stream>>>(cur, w2, counts, bases, tokl, wtl, out);
}